// Round 6
// baseline (229.558 us; speedup 1.0000x reference)
//
#include <hip/hip_runtime.h>
#include <hip/hip_bf16.h>

#define NN 10000
#define MP 10048        // 314*32, padded M for guard-free global_load_lds
#define RR 16
#define NBASE 30
#define EE 160000
#define KTOT 4352       // (RR+1)*256
#define HIDF 256
#define OUTF 128
#define NSEG (NN * RR)

typedef __attribute__((ext_vector_type(8))) short bf16x8;
typedef __attribute__((ext_vector_type(4))) short s16x4;
typedef __attribute__((ext_vector_type(4))) float f32x4;

static __device__ __forceinline__ short f2bf(float f) {
    union { float f; unsigned u; } v; v.f = f;
    unsigned r = v.u + 0x7FFFu + ((v.u >> 16) & 1u);
    return (short)(r >> 16);
}
static __device__ __forceinline__ float bf2f(short s) {
    union { unsigned u; float f; } v;
    v.u = ((unsigned)(unsigned short)s) << 16;
    return v.f;
}
static __device__ __forceinline__ void gl16(const short* g, short* l) {
    __builtin_amdgcn_global_load_lds((const __attribute__((address_space(1))) void*)g,
                                     (__attribute__((address_space(3))) void*)l, 16, 0, 0);
}

// ---- fused weight build + transpose: WT[o][k] bf16, k=r*256+i (r==16 -> root) ----
// One 32x32 tile per block; r is uniform per tile (k0 is 32-aligned, rel regions 256-aligned).
template <int OUT>
__global__ void wtr_k(const float* __restrict__ basis, const float* __restrict__ comp,
                      const float* __restrict__ root, short* __restrict__ WT) {
    __shared__ short t[32][34];
    const int k0 = blockIdx.x * 32, o0 = blockIdx.y * 32;
    const int tx = threadIdx.x & 31, ty = threadIdx.x >> 5;  // ty 0..7
    const int r = k0 >> 8;
    const int o = o0 + tx;
    #pragma unroll
    for (int dy = 0; dy < 32; dy += 8) {
        const int k = k0 + ty + dy, i = k & 255;
        float v;
        if (r < RR) {
            float s = 0.f;
            #pragma unroll
            for (int b = 0; b < NBASE; b++)
                s += comp[r * NBASE + b] * basis[((long)b * 256 + i) * OUT + o];
            v = s;
        } else {
            v = root[(long)i * OUT + o];
        }
        t[ty + dy][tx] = f2bf(v);
    }
    __syncthreads();
    #pragma unroll
    for (int dy = 0; dy < 32; dy += 8)
        WT[(long)(o0 + ty + dy) * KTOT + k0 + tx] = t[tx][ty + dy];
}

// ---- CSR build ----
__global__ void count_k(const int* __restrict__ dst, const int* __restrict__ et,
                        int* __restrict__ cnt) {
    int e = blockIdx.x * 256 + threadIdx.x;
    if (e < EE) atomicAdd(&cnt[dst[e] * RR + et[e]], 1);
}

__global__ void scan1_k(const int* __restrict__ cnt, int* __restrict__ incl,
                        int* __restrict__ bsum) {
    __shared__ int s[256];
    int i = blockIdx.x * 256 + threadIdx.x;
    int v = (i < NSEG) ? cnt[i] : 0;
    s[threadIdx.x] = v;
    __syncthreads();
    for (int off = 1; off < 256; off <<= 1) {
        int u = (threadIdx.x >= off) ? s[threadIdx.x - off] : 0;
        __syncthreads();
        s[threadIdx.x] += u;
        __syncthreads();
    }
    if (i < NSEG) incl[i] = s[threadIdx.x];
    if (threadIdx.x == 255) bsum[blockIdx.x] = s[255];
}

__global__ void scan2_k(int* __restrict__ bsum, int nb) {
    __shared__ int s[1024];
    int t = threadIdx.x;
    s[t] = (t < nb) ? bsum[t] : 0;
    __syncthreads();
    for (int off = 1; off < 1024; off <<= 1) {
        int u = (t >= off) ? s[t - off] : 0;
        __syncthreads();
        s[t] += u;
        __syncthreads();
    }
    if (t < nb) bsum[t] = s[t];
}

__global__ void scan3_k(const int* __restrict__ cnt, const int* __restrict__ incl,
                        const int* __restrict__ bsum, int* __restrict__ row_ptr,
                        int* __restrict__ fillpos) {
    int i = blockIdx.x * 256 + threadIdx.x;
    if (i >= NSEG) return;
    int off = (blockIdx.x > 0) ? bsum[blockIdx.x - 1] : 0;
    int ex = off + incl[i] - cnt[i];
    row_ptr[i] = ex;
    fillpos[i] = ex;
    if (i == 0) row_ptr[NSEG] = EE;
}

__global__ void fill_k(const int* __restrict__ src, const int* __restrict__ dst,
                       const int* __restrict__ et, int* __restrict__ fillpos,
                       int* __restrict__ esrc) {
    int e = blockIdx.x * 256 + threadIdx.x;
    if (e < EE) {
        int seg = dst[e] * RR + et[e];
        int p = atomicAdd(&fillpos[seg], 1);
        esrc[p] = src[e];
    }
}

// ---- X -> bf16 AND root-slot write ----
__global__ void cvtbf_root_k(const float* __restrict__ X, short* __restrict__ Y,
                             short* __restrict__ Abig) {
    int i = blockIdx.x * 256 + threadIdx.x;  // one per 4 cols
    if (i >= NN * 64) return;
    int m = i >> 6, g = i & 63;
    float4 v = *(const float4*)(X + (long)i * 4);
    s16x4 pk = { f2bf(v.x), f2bf(v.y), f2bf(v.z), f2bf(v.w) };
    *(s16x4*)&Y[(long)i * 4] = pk;
    *(s16x4*)&Abig[((long)m * 17 + 16) * 256 + g * 4] = pk;
}

// ---- gather-mean, 2 segments per wave, 16B/lane, bf16 in/out ----
__global__ void agg_k(const int* __restrict__ rp, const int* __restrict__ esrc,
                      const short* __restrict__ Xbf, short* __restrict__ Abig) {
    int wv = (blockIdx.x * 256 + threadIdx.x) >> 6;
    int lane = threadIdx.x & 63;
    int seg = wv * 2 + (lane >> 5);
    if (seg >= NSEG) return;
    int l5 = lane & 31;
    int b = rp[seg], e = rp[seg + 1];
    float acc[8] = {};
    for (int j = b; j < e; j++) {
        uint4 v = *(const uint4*)&Xbf[(long)esrc[j] * 256 + l5 * 8];
        const short* ps = (const short*)&v;
        #pragma unroll
        for (int q = 0; q < 8; q++) acc[q] += bf2f(ps[q]);
    }
    float inv = (e > b) ? 1.f / (float)(e - b) : 0.f;
    short out[8];
    #pragma unroll
    for (int q = 0; q < 8; q++) out[q] = f2bf(acc[q] * inv);
    *(uint4*)&Abig[((long)(seg >> 4) * 17 + (seg & 15)) * 256 + l5 * 8] = *(const uint4*)out;
}

// ---- GEMM partial: Cpart[z][m][o] = sum_{k in chunk z} Abig[m][k]*WT[o][k] ----
// BM=32, BN=full N (A read once), BK=64, 4 waves, 2-phase LDS double-buffer:
// stage(next) || compute(cur), one barrier per K-step (T3 minimum recipe).
// XOR swizzle: slot s of row r holds global 16B-chunk s^(r&7), both sides.
template <int BN, int KCH>
__global__ __launch_bounds__(256, BN == 256 ? 2 : 4)
void gemm_k(const short* __restrict__ A, const short* __restrict__ WT,
            float* __restrict__ Cpart) {
    constexpr int BM = 32;
    constexpr int WC = BN / 64;      // wave-cols (4 or 2)
    constexpr int WR = 4 / WC;       // wave-rows (1 or 2)
    constexpr int RPW = BM / WR;     // rows per wave (32 or 16)
    constexpr int FM = RPW / 16;     // m-frags (2 or 1)
    constexpr int BSR = BN / 32;     // Bs staging rounds

    __shared__ __align__(16) short As[2][BM * 64];
    __shared__ __align__(16) short Bs[2][BN * 64];

    const int tid = threadIdx.x;
    const int lane = tid & 63;
    const int w = tid >> 6;
    const int wr = w / WC, wc = w % WC;
    const int m0 = blockIdx.x * BM;
    const int kbase = blockIdx.y * KCH;

    const int al = lane & 15;
    const int cl = lane >> 4;

    // staging source offsets (write-side swizzle on global col, LDS linear)
    int gsrcA;
    { int row = tid >> 3; gsrcA = row * KTOT + (((tid & 7) ^ (row & 7)) << 3); }
    int gsrcB[BSR];
    #pragma unroll
    for (int i = 0; i < BSR; i++) {
        int ci = i * 256 + tid;
        int row = ci >> 3;
        gsrcB[i] = row * KTOT + (((ci & 7) ^ (row & 7)) << 3);
    }

    // read offsets (read-side swizzle, same involution)
    int aoff[FM][2], boff[4][2];
    #pragma unroll
    for (int fm = 0; fm < FM; fm++)
        #pragma unroll
        for (int k2 = 0; k2 < 2; k2++) {
            int row = wr * RPW + fm * 16 + al;
            int slot = ((k2 << 2) | cl) ^ (row & 7);
            aoff[fm][k2] = (row << 6) + (slot << 3);
        }
    #pragma unroll
    for (int fn = 0; fn < 4; fn++)
        #pragma unroll
        for (int k2 = 0; k2 < 2; k2++) {
            int row = wc * 64 + fn * 16 + al;
            int slot = ((k2 << 2) | cl) ^ (row & 7);
            boff[fn][k2] = (row << 6) + (slot << 3);
        }

    f32x4 acc[FM][4] = {};
    const short* abase = A + (long)m0 * KTOT + kbase;
    const short* bbase = WT + kbase;

    // prologue: stage tile 0 into buf 0
    gl16(abase + gsrcA, &As[0][w * 512]);
    #pragma unroll
    for (int i = 0; i < BSR; i++)
        gl16(bbase + gsrcB[i], &Bs[0][i * 2048 + w * 512]);
    __syncthreads();

    constexpr int NT = KCH / 64;
    for (int t = 0; t < NT; ++t) {
        const int cur = t & 1;
        if (t + 1 < NT) {  // stage next tile into other buffer (overlaps MFMA below)
            const int kk = (t + 1) * 64;
            gl16(abase + kk + gsrcA, &As[cur ^ 1][w * 512]);
            #pragma unroll
            for (int i = 0; i < BSR; i++)
                gl16(bbase + kk + gsrcB[i], &Bs[cur ^ 1][i * 2048 + w * 512]);
        }

        bf16x8 a[FM][2], b[4][2];
        #pragma unroll
        for (int fm = 0; fm < FM; fm++)
            #pragma unroll
            for (int k2 = 0; k2 < 2; k2++)
                a[fm][k2] = *(const bf16x8*)&As[cur][aoff[fm][k2]];
        #pragma unroll
        for (int fn = 0; fn < 4; fn++)
            #pragma unroll
            for (int k2 = 0; k2 < 2; k2++)
                b[fn][k2] = *(const bf16x8*)&Bs[cur][boff[fn][k2]];
        #pragma unroll
        for (int k2 = 0; k2 < 2; k2++)
            #pragma unroll
            for (int fm = 0; fm < FM; fm++)
                #pragma unroll
                for (int fn = 0; fn < 4; fn++)
                    acc[fm][fn] = __builtin_amdgcn_mfma_f32_16x16x32_bf16(
                        a[fm][k2], b[fn][k2], acc[fm][fn], 0, 0, 0);

        __syncthreads();  // drains next-tile loads (vmcnt 0) + guards LDS reuse
    }

    // epilogue: C/D frag col=lane&15, row=(lane>>4)*4+j
    const int r4 = (lane >> 4) << 2;
    #pragma unroll
    for (int fm = 0; fm < FM; fm++) {
        const int mbase = m0 + wr * RPW + fm * 16 + r4;
        #pragma unroll
        for (int j = 0; j < 4; j++) {
            const int m = mbase + j;
            if (m < NN) {
                float* cp = Cpart + ((long)blockIdx.y * NN + m) * BN + wc * 64 + al;
                #pragma unroll
                for (int fn = 0; fn < 4; fn++)
                    cp[fn * 16] = acc[fm][fn][j];
            }
        }
    }
}

// ---- reduce K-partials + bias (+ReLU); optional root-slot write for next layer ----
template <int NOUT, int KS, bool RELU, bool BF16OUT, bool ROOT>
__global__ void reduce_k(const float* __restrict__ Cpart, const float* __restrict__ bias,
                         void* __restrict__ out, short* __restrict__ Abig) {
    constexpr int G = NOUT / 4;
    int i = blockIdx.x * 256 + threadIdx.x;  // one per 4 cols
    if (i >= NN * G) return;
    int m = i / G, g = i % G;
    f32x4 sv = {};
    #pragma unroll
    for (int z = 0; z < KS; z++)
        sv += *(const f32x4*)&Cpart[((long)z * NN + m) * NOUT + g * 4];
    sv += *(const f32x4*)&bias[g * 4];
    if (RELU) {
        sv.x = fmaxf(sv.x, 0.f); sv.y = fmaxf(sv.y, 0.f);
        sv.z = fmaxf(sv.z, 0.f); sv.w = fmaxf(sv.w, 0.f);
    }
    if (BF16OUT) {
        s16x4 pk = { f2bf(sv.x), f2bf(sv.y), f2bf(sv.z), f2bf(sv.w) };
        *(s16x4*)((short*)out + (long)i * 4) = pk;
        if (ROOT)
            *(s16x4*)&Abig[((long)m * 17 + 16) * 256 + g * 4] = pk;
    } else {
        *(f32x4*)((float*)out + (long)i * 4) = sv;
    }
}

extern "C" void kernel_launch(void* const* d_in, const int* in_sizes, int n_in,
                              void* d_out, int out_size, void* d_ws, size_t ws_size,
                              hipStream_t stream) {
    const float* x      = (const float*)d_in[0];
    const int*   ei     = (const int*)d_in[1];
    const int*   et     = (const int*)d_in[2];
    const float* basis1 = (const float*)d_in[3];
    const float* comp1  = (const float*)d_in[4];
    const float* root1  = (const float*)d_in[5];
    const float* bias1  = (const float*)d_in[6];
    const float* basis2 = (const float*)d_in[7];
    const float* comp2  = (const float*)d_in[8];
    const float* root2  = (const float*)d_in[9];
    const float* bias2  = (const float*)d_in[10];
    const int* src = ei;
    const int* dst = ei + EE;

    char* p = (char*)d_ws;
    auto take = [&](size_t bytes) { char* q = p; p += (bytes + 255) & ~(size_t)255; return q; };
    short* Abig  = (short*)take((size_t)MP * 17 * 256 * 2);    // 87.4 MB (padded M)
    short* WT1   = (short*)take((size_t)HIDF * KTOT * 2);
    short* WT2   = (short*)take((size_t)OUTF * KTOT * 2);
    short* Xbf   = (short*)take((size_t)NN * 256 * 2);
    short* Hbf   = (short*)take((size_t)NN * 256 * 2);
    float* Cpart = (float*)take((size_t)4 * NN * 256 * 4);     // 41 MB, reused both layers
    int*   cnt   = (int*)take((size_t)NSEG * 4);
    int*   incl  = (int*)take((size_t)NSEG * 4);
    int*   rowp  = (int*)take((size_t)(NSEG + 1) * 4);
    int*   fpos  = (int*)take((size_t)NSEG * 4);
    int*   bsum  = (int*)take(1024 * 4);
    int*   esrc  = (int*)take((size_t)EE * 4);

    const int NB1 = (NSEG + 255) / 256;  // 625

    hipMemsetAsync(cnt, 0, (size_t)NSEG * 4, stream);

    // weights (fused build+transpose)
    {
        dim3 g1(KTOT / 32, HIDF / 32), g2(KTOT / 32, OUTF / 32);
        wtr_k<HIDF><<<g1, 256, 0, stream>>>(basis1, comp1, root1, WT1);
        wtr_k<OUTF><<<g2, 256, 0, stream>>>(basis2, comp2, root2, WT2);
    }

    // CSR
    count_k<<<(EE + 255) / 256, 256, 0, stream>>>(dst, et, cnt);
    scan1_k<<<NB1, 256, 0, stream>>>(cnt, incl, bsum);
    scan2_k<<<1, 1024, 0, stream>>>(bsum, NB1);
    scan3_k<<<NB1, 256, 0, stream>>>(cnt, incl, bsum, rowp, fpos);
    fill_k<<<(EE + 255) / 256, 256, 0, stream>>>(src, dst, et, fpos, esrc);

    // X -> bf16 (+ layer-1 root slot)
    cvtbf_root_k<<<(NN * 64 + 255) / 256, 256, 0, stream>>>(x, Xbf, Abig);

    // layer 1
    agg_k<<<(NSEG / 2 * 64 + 255) / 256, 256, 0, stream>>>(rowp, esrc, Xbf, Abig);
    {
        dim3 g(MP / 32, 4);  // KS=4, KCH=1088
        gemm_k<HIDF, 1088><<<g, 256, 0, stream>>>(Abig, WT1, Cpart);
    }
    // reduce1 writes Hbf AND the layer-2 root slot of Abig
    reduce_k<HIDF, 4, true, true, true><<<(NN * 64 + 255) / 256, 256, 0, stream>>>(
        Cpart, bias1, Hbf, Abig);

    // layer 2
    agg_k<<<(NSEG / 2 * 64 + 255) / 256, 256, 0, stream>>>(rowp, esrc, Hbf, Abig);
    {
        dim3 g(MP / 32, 4);  // KS=4, KCH=1088
        gemm_k<OUTF, 1088><<<g, 256, 0, stream>>>(Abig, WT2, Cpart);
    }
    reduce_k<OUTF, 4, false, false, false><<<(NN * 32 + 255) / 256, 256, 0, stream>>>(
        Cpart, bias2, (float*)d_out, nullptr);
}

// Round 7
// 185.434 us; speedup vs baseline: 1.2380x; 1.2380x over previous
//
#include <hip/hip_runtime.h>
#include <hip/hip_bf16.h>

#define NN 10000
#define MP 10048        // 157*64, padded M for guard-free global_load_lds
#define RR 16
#define NBASE 30
#define EE 160000
#define KTOT 4352       // (RR+1)*256 logical K
#define KSTR 4608       // padded K stride (18*256); pad cols 4352..4607 are zero in WT
#define HIDF 256
#define OUTF 128
#define NSEG (NN * RR)
#define KSPLIT 8
#define KCH 576         // KSTR/KSPLIT = 9*64

typedef __attribute__((ext_vector_type(8))) short bf16x8;
typedef __attribute__((ext_vector_type(4))) short s16x4;
typedef __attribute__((ext_vector_type(4))) float f32x4;

static __device__ __forceinline__ short f2bf(float f) {
    union { float f; unsigned u; } v; v.f = f;
    unsigned r = v.u + 0x7FFFu + ((v.u >> 16) & 1u);
    return (short)(r >> 16);
}
static __device__ __forceinline__ float bf2f(short s) {
    union { unsigned u; float f; } v;
    v.u = ((unsigned)(unsigned short)s) << 16;
    return v.f;
}
static __device__ __forceinline__ void gl16(const short* g, short* l) {
    __builtin_amdgcn_global_load_lds((const __attribute__((address_space(1))) void*)g,
                                     (__attribute__((address_space(3))) void*)l, 16, 0, 0);
}

// ---- fused weight build + transpose: WT[o][k] bf16, k=r*256+i ----
// r<16: basis-decomp; r==16: root; r==17 (K pad): zero.
template <int OUT>
__global__ void wtr_k(const float* __restrict__ basis, const float* __restrict__ comp,
                      const float* __restrict__ root, short* __restrict__ WT) {
    __shared__ short t[32][34];
    const int k0 = blockIdx.x * 32, o0 = blockIdx.y * 32;
    const int tx = threadIdx.x & 31, ty = threadIdx.x >> 5;  // ty 0..7
    const int r = k0 >> 8;
    const int o = o0 + tx;
    #pragma unroll
    for (int dy = 0; dy < 32; dy += 8) {
        const int k = k0 + ty + dy, i = k & 255;
        float v;
        if (r < RR) {
            float s = 0.f;
            #pragma unroll
            for (int b = 0; b < NBASE; b++)
                s += comp[r * NBASE + b] * basis[((long)b * 256 + i) * OUT + o];
            v = s;
        } else if (r == RR) {
            v = root[(long)i * OUT + o];
        } else {
            v = 0.f;   // K pad
        }
        t[ty + dy][tx] = f2bf(v);
    }
    __syncthreads();
    #pragma unroll
    for (int dy = 0; dy < 32; dy += 8)
        WT[(long)(o0 + ty + dy) * KSTR + k0 + tx] = t[tx][ty + dy];
}

// ---- CSR build ----
__global__ void count_k(const int* __restrict__ dst, const int* __restrict__ et,
                        int* __restrict__ cnt) {
    int e = blockIdx.x * 256 + threadIdx.x;
    if (e < EE) atomicAdd(&cnt[dst[e] * RR + et[e]], 1);
}

__global__ void scan1_k(const int* __restrict__ cnt, int* __restrict__ incl,
                        int* __restrict__ bsum) {
    __shared__ int s[256];
    int i = blockIdx.x * 256 + threadIdx.x;
    int v = (i < NSEG) ? cnt[i] : 0;
    s[threadIdx.x] = v;
    __syncthreads();
    for (int off = 1; off < 256; off <<= 1) {
        int u = (threadIdx.x >= off) ? s[threadIdx.x - off] : 0;
        __syncthreads();
        s[threadIdx.x] += u;
        __syncthreads();
    }
    if (i < NSEG) incl[i] = s[threadIdx.x];
    if (threadIdx.x == 255) bsum[blockIdx.x] = s[255];
}

__global__ void scan2_k(int* __restrict__ bsum, int nb) {
    __shared__ int s[1024];
    int t = threadIdx.x;
    s[t] = (t < nb) ? bsum[t] : 0;
    __syncthreads();
    for (int off = 1; off < 1024; off <<= 1) {
        int u = (t >= off) ? s[t - off] : 0;
        __syncthreads();
        s[t] += u;
        __syncthreads();
    }
    if (t < nb) bsum[t] = s[t];
}

__global__ void scan3_k(const int* __restrict__ cnt, const int* __restrict__ incl,
                        const int* __restrict__ bsum, int* __restrict__ row_ptr,
                        int* __restrict__ fillpos) {
    int i = blockIdx.x * 256 + threadIdx.x;
    if (i >= NSEG) return;
    int off = (blockIdx.x > 0) ? bsum[blockIdx.x - 1] : 0;
    int ex = off + incl[i] - cnt[i];
    row_ptr[i] = ex;
    fillpos[i] = ex;
    if (i == 0) row_ptr[NSEG] = EE;
}

__global__ void fill_k(const int* __restrict__ src, const int* __restrict__ dst,
                       const int* __restrict__ et, int* __restrict__ fillpos,
                       int* __restrict__ esrc) {
    int e = blockIdx.x * 256 + threadIdx.x;
    if (e < EE) {
        int seg = dst[e] * RR + et[e];
        int p = atomicAdd(&fillpos[seg], 1);
        esrc[p] = src[e];
    }
}

// ---- X -> bf16 AND root-slot write (Abig row stride = 18 slots) ----
__global__ void cvtbf_root_k(const float* __restrict__ X, short* __restrict__ Y,
                             short* __restrict__ Abig) {
    int i = blockIdx.x * 256 + threadIdx.x;  // one per 4 cols
    if (i >= NN * 64) return;
    int m = i >> 6, g = i & 63;
    float4 v = *(const float4*)(X + (long)i * 4);
    s16x4 pk = { f2bf(v.x), f2bf(v.y), f2bf(v.z), f2bf(v.w) };
    *(s16x4*)&Y[(long)i * 4] = pk;
    *(s16x4*)&Abig[((long)m * 18 + 16) * 256 + g * 4] = pk;
}

// ---- gather-mean, 2 segments per wave, 16B/lane, bf16 in/out ----
__global__ void agg_k(const int* __restrict__ rp, const int* __restrict__ esrc,
                      const short* __restrict__ Xbf, short* __restrict__ Abig) {
    int wv = (blockIdx.x * 256 + threadIdx.x) >> 6;
    int lane = threadIdx.x & 63;
    int seg = wv * 2 + (lane >> 5);
    if (seg >= NSEG) return;
    int l5 = lane & 31;
    int b = rp[seg], e = rp[seg + 1];
    float acc[8] = {};
    for (int j = b; j < e; j++) {
        uint4 v = *(const uint4*)&Xbf[(long)esrc[j] * 256 + l5 * 8];
        const short* ps = (const short*)&v;
        #pragma unroll
        for (int q = 0; q < 8; q++) acc[q] += bf2f(ps[q]);
    }
    float inv = (e > b) ? 1.f / (float)(e - b) : 0.f;
    short out[8];
    #pragma unroll
    for (int q = 0; q < 8; q++) out[q] = f2bf(acc[q] * inv);
    *(uint4*)&Abig[((long)(seg >> 4) * 18 + (seg & 15)) * 256 + l5 * 8] = *(const uint4*)out;
}

// ---- GEMM partial: Cpart[z][m][o] = sum_{k in chunk z} Abig[m][k]*WT[o][k] ----
// BM=64, BN=full N (A read once per chunk), BK=64, 4 waves, single-buffer
// (r5 structure — dbuf regressed in r6 by halving resident blocks).
// KS=8 via K-pad-to-4608 doubles the grid to 1256 blocks (~4.9/CU).
// XOR swizzle: LDS slot s of row r holds global 16B-chunk s^(r&7), both sides.
template <int BN>
__global__ __launch_bounds__(256, 4) void gemm_k(const short* __restrict__ A,
                                                 const short* __restrict__ WT,
                                                 float* __restrict__ Cpart) {
    constexpr int WC = BN / 64;      // wave-cols (4 or 2)
    constexpr int WR = 4 / WC;       // wave-rows (1 or 2)
    constexpr int RPW = 64 / WR;     // rows per wave (64 or 32)
    constexpr int FM = RPW / 16;     // m-frags (4 or 2)
    constexpr int BSR = BN / 32;     // Bs staging rounds (8 or 4)

    __shared__ __align__(16) short As[64 * 64];
    __shared__ __align__(16) short Bs[BN * 64];

    const int tid = threadIdx.x;
    const int lane = tid & 63;
    const int w = tid >> 6;
    const int wr = w / WC, wc = w % WC;
    const int m0 = blockIdx.x * 64;
    const int kbase = blockIdx.y * KCH;

    const int al = lane & 15;
    const int cl = lane >> 4;

    // staging source offsets (write-side swizzle on global col, LDS linear)
    int gsrcA[2];
    #pragma unroll
    for (int i = 0; i < 2; i++) {
        int ci = i * 256 + tid;
        int row = ci >> 3;
        gsrcA[i] = row * KSTR + (((ci & 7) ^ (row & 7)) << 3);
    }
    int gsrcB[BSR];
    #pragma unroll
    for (int i = 0; i < BSR; i++) {
        int ci = i * 256 + tid;
        int row = ci >> 3;
        gsrcB[i] = row * KSTR + (((ci & 7) ^ (row & 7)) << 3);
    }

    // read offsets (read-side swizzle, same involution)
    int aoff[FM][2], boff[4][2];
    #pragma unroll
    for (int fm = 0; fm < FM; fm++)
        #pragma unroll
        for (int k2 = 0; k2 < 2; k2++) {
            int row = wr * RPW + fm * 16 + al;
            int slot = ((k2 << 2) | cl) ^ (row & 7);
            aoff[fm][k2] = (row << 6) + (slot << 3);
        }
    #pragma unroll
    for (int fn = 0; fn < 4; fn++)
        #pragma unroll
        for (int k2 = 0; k2 < 2; k2++) {
            int row = wc * 64 + fn * 16 + al;
            int slot = ((k2 << 2) | cl) ^ (row & 7);
            boff[fn][k2] = (row << 6) + (slot << 3);
        }

    f32x4 acc[FM][4] = {};
    const short* abase = A + (long)m0 * KSTR + kbase;
    const short* bbase = WT + kbase;

    for (int kk = 0; kk < KCH; kk += 64) {
        #pragma unroll
        for (int i = 0; i < 2; i++)
            gl16(abase + kk + gsrcA[i], &As[i * 2048 + w * 512]);
        #pragma unroll
        for (int i = 0; i < BSR; i++)
            gl16(bbase + kk + gsrcB[i], &Bs[i * 2048 + w * 512]);
        __syncthreads();

        bf16x8 a[FM][2], b[4][2];
        #pragma unroll
        for (int fm = 0; fm < FM; fm++)
            #pragma unroll
            for (int k2 = 0; k2 < 2; k2++)
                a[fm][k2] = *(const bf16x8*)&As[aoff[fm][k2]];
        #pragma unroll
        for (int fn = 0; fn < 4; fn++)
            #pragma unroll
            for (int k2 = 0; k2 < 2; k2++)
                b[fn][k2] = *(const bf16x8*)&Bs[boff[fn][k2]];
        #pragma unroll
        for (int k2 = 0; k2 < 2; k2++)
            #pragma unroll
            for (int fm = 0; fm < FM; fm++)
                #pragma unroll
                for (int fn = 0; fn < 4; fn++)
                    acc[fm][fn] = __builtin_amdgcn_mfma_f32_16x16x32_bf16(
                        a[fm][k2], b[fn][k2], acc[fm][fn], 0, 0, 0);
        __syncthreads();
    }

    // epilogue: C/D frag col=lane&15, row=(lane>>4)*4+j
    const int r4 = (lane >> 4) << 2;
    #pragma unroll
    for (int fm = 0; fm < FM; fm++) {
        const int mbase = m0 + wr * RPW + fm * 16 + r4;
        #pragma unroll
        for (int j = 0; j < 4; j++) {
            const int m = mbase + j;
            if (m < NN) {
                float* cp = Cpart + ((long)blockIdx.y * NN + m) * BN + wc * 64 + al;
                #pragma unroll
                for (int fn = 0; fn < 4; fn++)
                    cp[fn * 16] = acc[fm][fn][j];
            }
        }
    }
}

// ---- reduce K-partials + bias (+ReLU); optional root-slot write for next layer ----
template <int NOUT, int KS, bool RELU, bool BF16OUT, bool ROOT>
__global__ void reduce_k(const float* __restrict__ Cpart, const float* __restrict__ bias,
                         void* __restrict__ out, short* __restrict__ Abig) {
    constexpr int G = NOUT / 4;
    int i = blockIdx.x * 256 + threadIdx.x;  // one per 4 cols
    if (i >= NN * G) return;
    int m = i / G, g = i % G;
    f32x4 sv = {};
    #pragma unroll
    for (int z = 0; z < KS; z++)
        sv += *(const f32x4*)&Cpart[((long)z * NN + m) * NOUT + g * 4];
    sv += *(const f32x4*)&bias[g * 4];
    if (RELU) {
        sv.x = fmaxf(sv.x, 0.f); sv.y = fmaxf(sv.y, 0.f);
        sv.z = fmaxf(sv.z, 0.f); sv.w = fmaxf(sv.w, 0.f);
    }
    if (BF16OUT) {
        s16x4 pk = { f2bf(sv.x), f2bf(sv.y), f2bf(sv.z), f2bf(sv.w) };
        *(s16x4*)((short*)out + (long)i * 4) = pk;
        if (ROOT)
            *(s16x4*)&Abig[((long)m * 18 + 16) * 256 + g * 4] = pk;
    } else {
        *(f32x4*)((float*)out + (long)i * 4) = sv;
    }
}

extern "C" void kernel_launch(void* const* d_in, const int* in_sizes, int n_in,
                              void* d_out, int out_size, void* d_ws, size_t ws_size,
                              hipStream_t stream) {
    const float* x      = (const float*)d_in[0];
    const int*   ei     = (const int*)d_in[1];
    const int*   et     = (const int*)d_in[2];
    const float* basis1 = (const float*)d_in[3];
    const float* comp1  = (const float*)d_in[4];
    const float* root1  = (const float*)d_in[5];
    const float* bias1  = (const float*)d_in[6];
    const float* basis2 = (const float*)d_in[7];
    const float* comp2  = (const float*)d_in[8];
    const float* root2  = (const float*)d_in[9];
    const float* bias2  = (const float*)d_in[10];
    const int* src = ei;
    const int* dst = ei + EE;

    char* p = (char*)d_ws;
    auto take = [&](size_t bytes) { char* q = p; p += (bytes + 255) & ~(size_t)255; return q; };
    short* Abig  = (short*)take((size_t)MP * 18 * 256 * 2);    // 92.6 MB ([m][18][256], slot17=K pad)
    short* WT1   = (short*)take((size_t)HIDF * KSTR * 2);      // 2.36 MB
    short* WT2   = (short*)take((size_t)OUTF * KSTR * 2);      // 1.18 MB
    short* Xbf   = (short*)take((size_t)NN * 256 * 2);         // 5.12 MB; reused as Hbf after layer 1
    float* Cpart = (float*)take((size_t)KSPLIT * NN * 256 * 4);// 81.9 MB
    int*   cnt   = (int*)take((size_t)NSEG * 4);
    int*   incl  = (int*)take((size_t)NSEG * 4);
    int*   rowp  = (int*)take((size_t)(NSEG + 1) * 4);
    int*   fpos  = (int*)take((size_t)NSEG * 4);
    int*   bsum  = (int*)take(1024 * 4);
    int*   esrc  = (int*)take((size_t)EE * 4);

    const int NB1 = (NSEG + 255) / 256;  // 625

    hipMemsetAsync(cnt, 0, (size_t)NSEG * 4, stream);

    // weights (fused build+transpose, K-pad rows zeroed)
    {
        dim3 g1(KSTR / 32, HIDF / 32), g2(KSTR / 32, OUTF / 32);
        wtr_k<HIDF><<<g1, 256, 0, stream>>>(basis1, comp1, root1, WT1);
        wtr_k<OUTF><<<g2, 256, 0, stream>>>(basis2, comp2, root2, WT2);
    }

    // CSR
    count_k<<<(EE + 255) / 256, 256, 0, stream>>>(dst, et, cnt);
    scan1_k<<<NB1, 256, 0, stream>>>(cnt, incl, bsum);
    scan2_k<<<1, 1024, 0, stream>>>(bsum, NB1);
    scan3_k<<<NB1, 256, 0, stream>>>(cnt, incl, bsum, rowp, fpos);
    fill_k<<<(EE + 255) / 256, 256, 0, stream>>>(src, dst, et, fpos, esrc);

    // X -> bf16 (+ layer-1 root slot)
    cvtbf_root_k<<<(NN * 64 + 255) / 256, 256, 0, stream>>>(x, Xbf, Abig);

    // layer 1
    agg_k<<<(NSEG / 2 * 64 + 255) / 256, 256, 0, stream>>>(rowp, esrc, Xbf, Abig);
    {
        dim3 g(MP / 64, KSPLIT);
        gemm_k<HIDF><<<g, 256, 0, stream>>>(Abig, WT1, Cpart);
    }
    // reduce1 writes H (into Xbf) AND the layer-2 root slot of Abig
    reduce_k<HIDF, KSPLIT, true, true, true><<<(NN * 64 + 255) / 256, 256, 0, stream>>>(
        Cpart, bias1, Xbf, Abig);

    // layer 2
    agg_k<<<(NSEG / 2 * 64 + 255) / 256, 256, 0, stream>>>(rowp, esrc, Xbf, Abig);
    {
        dim3 g(MP / 64, KSPLIT);
        gemm_k<OUTF><<<g, 256, 0, stream>>>(Abig, WT2, Cpart);
    }
    reduce_k<OUTF, KSPLIT, false, false, false><<<(NN * 32 + 255) / 256, 256, 0, stream>>>(
        Cpart, bias2, (float*)d_out, nullptr);
}